// Round 4
// baseline (526.722 us; speedup 1.0000x reference)
//
#include <hip/hip_runtime.h>

#define SEQ   200
#define BATCH 4096
#define EMB   100
#define HID   300
#define NH1   256
#define BM    16
#define HP    328            // halves per h row: 320 + 8 pad; 656 B (16B-aligned), 164 words % 32 = 4
#define NHF   10             // h frags: K = 320 (h 0..299, zeros 300..319)
#define NXF   4              // xe frags: K = 128 (valid 0..99, rest zero)
#define NT    3              // col-tiles per wave; 8 waves * 3 * 16 = 384 cols (300 real)
#define H1P   260

typedef _Float16 half8 __attribute__((ext_vector_type(8)));
typedef float floatx4 __attribute__((ext_vector_type(4)));

__device__ __forceinline__ float fast_tanh(float x) {
    float e = __expf(2.0f * x);
    float r = __builtin_amdgcn_rcpf(e + 1.0f);
    return 1.0f - 2.0f * r;
}

__global__ void __launch_bounds__(512)
rnn_fused(const int* __restrict__ x, const float* __restrict__ emb,
          const float* __restrict__ W_ih, const float* __restrict__ b_ih,
          const float* __restrict__ W_hh, const float* __restrict__ b_hh,
          const float* __restrict__ W1, const float* __restrict__ b1,
          const float* __restrict__ W2, const float* __restrict__ b2,
          float* __restrict__ out)
{
    __shared__ _Float16 u[2][BM][HP];    // double-buffered h (fp16), pads stay zero
    __shared__ int      xs[SEQ * BM];    // all token indices for this block
    __shared__ float    h1s[BM][H1P];

    const int tid  = threadIdx.x;
    const int lane = tid & 63;
    const int w    = tid >> 6;           // wave id 0..7
    const int ln15 = lane & 15;
    const int q    = lane >> 4;          // 0..3
    const int row0 = blockIdx.x * BM;

    // zero both u buffers (h pads must be 0 and stay 0)
    for (int i = tid; i < 2 * BM * HP / 2; i += 512) ((unsigned int*)u)[i] = 0u;
    // stage all x indices for this block: 200*16 ints
    for (int i = tid; i < SEQ * BM; i += 512)
        xs[i] = x[(size_t)(i >> 4) * BATCH + row0 + (i & 15)];

    // ---- weights resident in registers (B-frag layout: n = (3w+tt)*16+ln15, k = kk*32+q*8+j)
    half8 Wih[NT][NXF];
    half8 Whh[NT][NHF];
    float biasv[NT];
#pragma unroll
    for (int tt = 0; tt < NT; ++tt) {
        const int n = (3 * w + tt) * 16 + ln15;
        biasv[tt] = (n < HID) ? (b_ih[n] + b_hh[n]) : 0.0f;
#pragma unroll
        for (int kk = 0; kk < NXF; ++kk) {
            union { half8 h; unsigned int d[4]; } cv;
#pragma unroll
            for (int j = 0; j < 8; ++j) {
                const int k = kk * 32 + q * 8 + j;
                cv.h[j] = (_Float16)((n < HID && k < EMB) ? W_ih[n * EMB + k] : 0.0f);
            }
            asm volatile("" : "+v"(cv.d[0]), "+v"(cv.d[1]), "+v"(cv.d[2]), "+v"(cv.d[3]));
            Wih[tt][kk] = cv.h;
        }
#pragma unroll
        for (int kk = 0; kk < NHF; ++kk) {
            union { half8 h; unsigned int d[4]; } cv;
#pragma unroll
            for (int j = 0; j < 8; ++j) {
                const int k = kk * 32 + q * 8 + j;
                cv.h[j] = (_Float16)((n < HID && k < HID) ? W_hh[n * HID + k] : 0.0f);
            }
            asm volatile("" : "+v"(cv.d[0]), "+v"(cv.d[1]), "+v"(cv.d[2]), "+v"(cv.d[3]));
            Whh[tt][kk] = cv.h;
        }
    }
    __syncthreads();   // xs + zeroed u visible

    // ---- prime xe A-frags for t=0 (direct global gather, fp32 -> fp16 regs)
    // A[m=ln15][k=q*8+j], k = kk*32+q*8+j; frags 0..2 fully valid (k<=95), frag 3: q==0,j<4 only
    half8 xeA[NXF];
    {
        const float* pe = emb + (size_t)xs[ln15] * EMB;
        float4 p0a = ((const float4*)(pe + 0 * 32 + q * 8))[0];
        float4 p0b = ((const float4*)(pe + 0 * 32 + q * 8))[1];
        float4 p1a = ((const float4*)(pe + 1 * 32 + q * 8))[0];
        float4 p1b = ((const float4*)(pe + 1 * 32 + q * 8))[1];
        float4 p2a = ((const float4*)(pe + 2 * 32 + q * 8))[0];
        float4 p2b = ((const float4*)(pe + 2 * 32 + q * 8))[1];
        float4 p3  = (q == 0) ? ((const float4*)(pe + 96))[0] : float4{0, 0, 0, 0};
        half8 f0, f1, f2, f3;
        f0[0]=(_Float16)p0a.x; f0[1]=(_Float16)p0a.y; f0[2]=(_Float16)p0a.z; f0[3]=(_Float16)p0a.w;
        f0[4]=(_Float16)p0b.x; f0[5]=(_Float16)p0b.y; f0[6]=(_Float16)p0b.z; f0[7]=(_Float16)p0b.w;
        f1[0]=(_Float16)p1a.x; f1[1]=(_Float16)p1a.y; f1[2]=(_Float16)p1a.z; f1[3]=(_Float16)p1a.w;
        f1[4]=(_Float16)p1b.x; f1[5]=(_Float16)p1b.y; f1[6]=(_Float16)p1b.z; f1[7]=(_Float16)p1b.w;
        f2[0]=(_Float16)p2a.x; f2[1]=(_Float16)p2a.y; f2[2]=(_Float16)p2a.z; f2[3]=(_Float16)p2a.w;
        f2[4]=(_Float16)p2b.x; f2[5]=(_Float16)p2b.y; f2[6]=(_Float16)p2b.z; f2[7]=(_Float16)p2b.w;
        f3[0]=(_Float16)p3.x;  f3[1]=(_Float16)p3.y;  f3[2]=(_Float16)p3.z;  f3[3]=(_Float16)p3.w;
        f3[4]=(_Float16)0.0f;  f3[5]=(_Float16)0.0f;  f3[6]=(_Float16)0.0f;  f3[7]=(_Float16)0.0f;
        xeA[0] = f0; xeA[1] = f1; xeA[2] = f2; xeA[3] = f3;
    }

    for (int t = 0; t < SEQ; ++t) {
        const int p = t & 1;
        _Float16 (*cur)[HP] = u[p];
        _Float16 (*nxt)[HP] = u[1 - p];

        // issue xe_{t+1} gather FIRST — vmcnt wait lands after the MFMA phase
        float4 p0a, p0b, p1a, p1b, p2a, p2b, p3;
        const bool has = (t + 1 < SEQ);
        if (has) {
            const float* pe = emb + (size_t)xs[(t + 1) * BM + ln15] * EMB;
            p0a = ((const float4*)(pe + 0 * 32 + q * 8))[0];
            p0b = ((const float4*)(pe + 0 * 32 + q * 8))[1];
            p1a = ((const float4*)(pe + 1 * 32 + q * 8))[0];
            p1b = ((const float4*)(pe + 1 * 32 + q * 8))[1];
            p2a = ((const float4*)(pe + 2 * 32 + q * 8))[0];
            p2b = ((const float4*)(pe + 2 * 32 + q * 8))[1];
            p3  = (q == 0) ? ((const float4*)(pe + 96))[0] : float4{0, 0, 0, 0};
        }

        floatx4 acc[NT];
#pragma unroll
        for (int tt = 0; tt < NT; ++tt) {
            const float b = biasv[tt];
            acc[tt][0] = b; acc[tt][1] = b; acc[tt][2] = b; acc[tt][3] = b;
        }
        // xe part: no dependency on h_t — fills the pipe while first ds_read completes
#pragma unroll
        for (int kk = 0; kk < NXF; ++kk)
#pragma unroll
            for (int tt = 0; tt < NT; ++tt)
                acc[tt] = __builtin_amdgcn_mfma_f32_16x16x32_f16(xeA[kk], Wih[tt][kk], acc[tt], 0, 0, 0);
        // h part: 10 frags from LDS
#pragma unroll
        for (int kk = 0; kk < NHF; ++kk) {
            const half8 a = *(const half8*)&cur[ln15][kk * 32 + q * 8];
#pragma unroll
            for (int tt = 0; tt < NT; ++tt)
                acc[tt] = __builtin_amdgcn_mfma_f32_16x16x32_f16(a, Whh[tt][kk], acc[tt], 0, 0, 0);
        }

        // convert gathered xe_{t+1} into A-frags for next step
        if (has) {
            half8 f0, f1, f2, f3;
            f0[0]=(_Float16)p0a.x; f0[1]=(_Float16)p0a.y; f0[2]=(_Float16)p0a.z; f0[3]=(_Float16)p0a.w;
            f0[4]=(_Float16)p0b.x; f0[5]=(_Float16)p0b.y; f0[6]=(_Float16)p0b.z; f0[7]=(_Float16)p0b.w;
            f1[0]=(_Float16)p1a.x; f1[1]=(_Float16)p1a.y; f1[2]=(_Float16)p1a.z; f1[3]=(_Float16)p1a.w;
            f1[4]=(_Float16)p1b.x; f1[5]=(_Float16)p1b.y; f1[6]=(_Float16)p1b.z; f1[7]=(_Float16)p1b.w;
            f2[0]=(_Float16)p2a.x; f2[1]=(_Float16)p2a.y; f2[2]=(_Float16)p2a.z; f2[3]=(_Float16)p2a.w;
            f2[4]=(_Float16)p2b.x; f2[5]=(_Float16)p2b.y; f2[6]=(_Float16)p2b.z; f2[7]=(_Float16)p2b.w;
            f3[0]=(_Float16)p3.x;  f3[1]=(_Float16)p3.y;  f3[2]=(_Float16)p3.z;  f3[3]=(_Float16)p3.w;
            f3[4]=(_Float16)0.0f;  f3[5]=(_Float16)0.0f;  f3[6]=(_Float16)0.0f;  f3[7]=(_Float16)0.0f;
            xeA[0] = f0; xeA[1] = f1; xeA[2] = f2; xeA[3] = f3;
        }

        // tanh + write h_{t+1} (C/D layout: row = q*4 + r, col = (3w+tt)*16 + ln15)
#pragma unroll
        for (int tt = 0; tt < NT; ++tt) {
            const int n = (3 * w + tt) * 16 + ln15;
            if (n < HID) {
#pragma unroll
                for (int r = 0; r < 4; ++r)
                    nxt[q * 4 + r][n] = (_Float16)fast_tanh(acc[tt][r]);
            }
        }
        __syncthreads();   // single barrier per step
    }

    // ---- head: h1 = relu(h @ W1^T + b1); final h lives in u[SEQ & 1] == u[0]
    {
        _Float16 (*hf)[HP] = u[SEQ & 1];
        floatx4 hacc[2];
        int ncol[2];
#pragma unroll
        for (int tt = 0; tt < 2; ++tt) {
            const int n = (w * 2 + tt) * 16 + ln15;
            ncol[tt] = n;
            const float b = b1[n];
            hacc[tt][0] = b; hacc[tt][1] = b; hacc[tt][2] = b; hacc[tt][3] = b;
        }
#pragma unroll
        for (int kk = 0; kk < NHF; ++kk) {
            const half8 a = *(const half8*)&hf[ln15][kk * 32 + q * 8];
#pragma unroll
            for (int tt = 0; tt < 2; ++tt) {
                half8 bv;
#pragma unroll
                for (int j = 0; j < 8; ++j) {
                    const int k = kk * 32 + q * 8 + j;
                    bv[j] = (_Float16)((k < HID) ? W1[ncol[tt] * HID + k] : 0.0f);
                }
                hacc[tt] = __builtin_amdgcn_mfma_f32_16x16x32_f16(a, bv, hacc[tt], 0, 0, 0);
            }
        }
#pragma unroll
        for (int tt = 0; tt < 2; ++tt)
#pragma unroll
            for (int r = 0; r < 4; ++r)
                h1s[q * 4 + r][ncol[tt]] = fmaxf(hacc[tt][r], 0.0f);
    }
    __syncthreads();

    // ---- out = h1 @ W2^T + b2: 16 rows x 2 cols
    if (tid < 32) {
        const int r = tid & 15, o = tid >> 4;
        float a = b2[o];
        const float* ww = W2 + (size_t)o * NH1;
        for (int k = 0; k < NH1; ++k) a += h1s[r][k] * ww[k];
        out[(size_t)(row0 + r) * 2 + o] = a;
    }
}

extern "C" void kernel_launch(void* const* d_in, const int* in_sizes, int n_in,
                              void* d_out, int out_size, void* d_ws, size_t ws_size,
                              hipStream_t stream) {
    const int*   x    = (const int*)d_in[0];
    const float* emb  = (const float*)d_in[1];
    const float* W_ih = (const float*)d_in[2];
    const float* b_ih = (const float*)d_in[3];
    const float* W_hh = (const float*)d_in[4];
    const float* b_hh = (const float*)d_in[5];
    const float* W1   = (const float*)d_in[6];
    const float* b1   = (const float*)d_in[7];
    const float* W2   = (const float*)d_in[8];
    const float* b2   = (const float*)d_in[9];
    float* outp = (float*)d_out;

    hipLaunchKernelGGL(rnn_fused, dim3(BATCH / BM), dim3(512), 0, stream,
                       x, emb, W_ih, b_ih, W_hh, b_hh, W1, b1, W2, b2, outp);
}

// Round 5
// 409.143 us; speedup vs baseline: 1.2874x; 1.2874x over previous
//
#include <hip/hip_runtime.h>

#define SEQ   200
#define BATCH 4096
#define EMB   100
#define HID   300
#define NH1   256
#define BM    16
#define HOFF  112            // h starts at half-offset 112 (16B-aligned)
#define UP    440            // halves per u row: 112 + 320 + 8 pad; 880 B, 16B-aligned
#define NFRAG 13             // K = 416 = 13*32 (xe 0..99, zeros 100..111, h 112..411, zeros)
#define NTMAX 3
#define NHF   10
#define H1P   260

typedef _Float16 half8 __attribute__((ext_vector_type(8)));
typedef _Float16 half4h __attribute__((ext_vector_type(4)));
typedef float floatx4 __attribute__((ext_vector_type(4)));

__device__ __forceinline__ float fast_tanh(float x) {
    float e = __expf(2.0f * x);
    float r = __builtin_amdgcn_rcpf(e + 1.0f);
    return 1.0f - 2.0f * r;
}

__global__ void __launch_bounds__(512)
rnn_fused(const int* __restrict__ x, const float* __restrict__ emb,
          const float* __restrict__ W_ih, const float* __restrict__ b_ih,
          const float* __restrict__ W_hh, const float* __restrict__ b_hh,
          const float* __restrict__ W1, const float* __restrict__ b1,
          const float* __restrict__ W2, const float* __restrict__ b2,
          float* __restrict__ out)
{
    __shared__ _Float16 u[2][BM][UP];    // double-buffered [xe(100)|pad|h(300)|pad] fp16
    __shared__ int      xs[SEQ * BM];
    __shared__ float    h1s[BM][H1P];

    const int tid  = threadIdx.x;
    const int lane = tid & 63;
    const int w    = tid >> 6;           // wave id 0..7
    const int ln15 = lane & 15;
    const int q    = lane >> 4;          // 0..3
    const int row0 = blockIdx.x * BM;

    // 19 tiles of 16 cols cover 304 >= 300: waves 0-2 get 3 tiles, waves 3-7 get 2
    const int nt = (w < 3) ? 3 : 2;
    const int t0 = (w < 3) ? 3 * w : 2 * w + 3;

    // zero both u buffers (pads must be 0)
    for (int i = tid; i < 2 * BM * UP / 2; i += 512) ((unsigned int*)u)[i] = 0u;
    for (int i = tid; i < SEQ * BM; i += 512)
        xs[i] = x[(size_t)(i >> 4) * BATCH + row0 + (i & 15)];

    // ---- W resident in registers. Used as the A operand: lane ln15 holds
    // W row n=(t0+tt)*16+ln15, k = kk*32 + q*8 + j. (Same per-lane layout as a B-frag.)
    half8   Wb[NTMAX][NFRAG];
    floatx4 biasv[NTMAX];                // bias for output cols (t0+tt)*16 + 4q + r
#pragma unroll
    for (int tt = 0; tt < NTMAX; ++tt) {
        const int nb = (t0 + tt) * 16;
#pragma unroll
        for (int r = 0; r < 4; ++r) {
            const int col = nb + 4 * q + r;
            biasv[tt][r] = (col < HID) ? (b_ih[col] + b_hh[col]) : 0.0f;
        }
        const int n = nb + ln15;
#pragma unroll
        for (int kk = 0; kk < NFRAG; ++kk) {
            union { half8 h; unsigned int d[4]; } cv;
#pragma unroll
            for (int j = 0; j < 8; ++j) {
                const int k = kk * 32 + q * 8 + j;
                float v = 0.0f;
                if (n < HID) {
                    if (k < EMB)                          v = W_ih[n * EMB + k];
                    else if (k >= HOFF && k < HOFF + HID) v = W_hh[n * HID + (k - HOFF)];
                }
                cv.h[j] = (_Float16)v;
            }
            asm volatile("" : "+v"(cv.d[0]), "+v"(cv.d[1]), "+v"(cv.d[2]), "+v"(cv.d[3]));
            Wb[tt][kk] = cv.h;
        }
    }
    __syncthreads();

    // xe for t=0 into u[0]: 16 rows x 25 float4, threads 0..399
    const int gr = tid / 25, gc = tid - gr * 25;
    if (tid < 400) {
        const int idx = xs[gr];
        const float4 f = ((const float4*)emb)[(size_t)idx * 25 + gc];
        half4h hv; hv[0] = (_Float16)f.x; hv[1] = (_Float16)f.y;
                   hv[2] = (_Float16)f.z; hv[3] = (_Float16)f.w;
        *(half4h*)&u[0][gr][gc * 4] = hv;
    }
    __syncthreads();

    for (int t = 0; t < SEQ; ++t) {
        const int p = t & 1;
        _Float16 (*cur)[UP] = u[p];
        _Float16 (*nxt)[UP] = u[1 - p];

        // issue xe_{t+1} gather first — vmcnt wait lands after the MFMA phase
        float4 pf;
        const bool do_pf = (t + 1 < SEQ) && (tid < 400);
        if (do_pf) {
            const int idx = xs[(t + 1) * BM + gr];
            pf = ((const float4*)emb)[(size_t)idx * 25 + gc];
        }

        floatx4 acc[NTMAX];
#pragma unroll
        for (int tt = 0; tt < NTMAX; ++tt) acc[tt] = biasv[tt];

#pragma unroll
        for (int kk = 0; kk < NFRAG; ++kk) {
            const half8 a = *(const half8*)&cur[ln15][kk * 32 + q * 8];
#pragma unroll
            for (int tt = 0; tt < NTMAX; ++tt)
                if (tt < nt)   // wave-uniform
                    acc[tt] = __builtin_amdgcn_mfma_f32_16x16x32_f16(Wb[tt][kk], a, acc[tt], 0, 0, 0);
        }

        if (do_pf) {
            half4h hv; hv[0] = (_Float16)pf.x; hv[1] = (_Float16)pf.y;
                       hv[2] = (_Float16)pf.z; hv[3] = (_Float16)pf.w;
            *(half4h*)&nxt[gr][gc * 4] = hv;
        }
        // transposed D: lane ln15 = batch row, cols (t0+tt)*16 + 4q + r -> packed b64 write.
        // cols >= HID land in the zero-weight pad (exact zeros), still < UP.
#pragma unroll
        for (int tt = 0; tt < NTMAX; ++tt) {
            if (tt < nt) {
                half4h hv;
#pragma unroll
                for (int r = 0; r < 4; ++r) hv[r] = (_Float16)fast_tanh(acc[tt][r]);
                *(half4h*)&nxt[ln15][HOFF + (t0 + tt) * 16 + 4 * q] = hv;
            }
        }
        __syncthreads();   // single barrier per step
    }

    // ---- head: h1 = relu(h @ W1^T + b1); final h lives in u[SEQ & 1] == u[0]
    {
        _Float16 (*hf)[UP] = u[SEQ & 1];
        floatx4 hacc[2];
        int ncol[2];
#pragma unroll
        for (int tt = 0; tt < 2; ++tt) {
            const int n = (w * 2 + tt) * 16 + ln15;
            ncol[tt] = n;
            const float b = b1[n];
            hacc[tt][0] = b; hacc[tt][1] = b; hacc[tt][2] = b; hacc[tt][3] = b;
        }
#pragma unroll
        for (int kk = 0; kk < NHF; ++kk) {
            const half8 a = *(const half8*)&hf[ln15][HOFF + kk * 32 + q * 8];
#pragma unroll
            for (int tt = 0; tt < 2; ++tt) {
                half8 bv;
#pragma unroll
                for (int j = 0; j < 8; ++j) {
                    const int k = kk * 32 + q * 8 + j;
                    bv[j] = (_Float16)((k < HID) ? W1[ncol[tt] * HID + k] : 0.0f);
                }
                hacc[tt] = __builtin_amdgcn_mfma_f32_16x16x32_f16(a, bv, hacc[tt], 0, 0, 0);
            }
        }
#pragma unroll
        for (int tt = 0; tt < 2; ++tt)
#pragma unroll
            for (int r = 0; r < 4; ++r)
                h1s[q * 4 + r][ncol[tt]] = fmaxf(hacc[tt][r], 0.0f);
    }
    __syncthreads();

    // ---- out = h1 @ W2^T + b2: 16 rows x 2 cols
    if (tid < 32) {
        const int r = tid & 15, o = tid >> 4;
        float a = b2[o];
        const float* ww = W2 + (size_t)o * NH1;
        for (int k = 0; k < NH1; ++k) a += h1s[r][k] * ww[k];
        out[(size_t)(row0 + r) * 2 + o] = a;
    }
}

extern "C" void kernel_launch(void* const* d_in, const int* in_sizes, int n_in,
                              void* d_out, int out_size, void* d_ws, size_t ws_size,
                              hipStream_t stream) {
    const int*   x    = (const int*)d_in[0];
    const float* emb  = (const float*)d_in[1];
    const float* W_ih = (const float*)d_in[2];
    const float* b_ih = (const float*)d_in[3];
    const float* W_hh = (const float*)d_in[4];
    const float* b_hh = (const float*)d_in[5];
    const float* W1   = (const float*)d_in[6];
    const float* b1   = (const float*)d_in[7];
    const float* W2   = (const float*)d_in[8];
    const float* b2   = (const float*)d_in[9];
    float* outp = (float*)d_out;

    hipLaunchKernelGGL(rnn_fused, dim3(BATCH / BM), dim3(512), 0, stream,
                       x, emb, W_ih, b_ih, W_hh, b_hh, W1, b1, W2, b2, outp);
}

// Round 6
// 394.283 us; speedup vs baseline: 1.3359x; 1.0377x over previous
//
#include <hip/hip_runtime.h>

#define SEQ   200
#define BATCH 4096
#define EMB   100
#define HID   300
#define NH1   256
#define BM    16
#define NFRAG 13             // K = 416: xe k=0..99 | zeros 100..111 | h k=112..411 | zeros
#define FRB   14             // allocated frag blocks; block 13 stays zero (head reads)
#define FB    1024           // bytes per frag block (32 k x 16 rows x 2B)
#define BUFB  (FRB * FB)     // bytes per u buffer
#define NTMAX 3
#define NHF   10
#define H1P   260
#define PD    5              // read-pipeline depth

typedef _Float16 half8 __attribute__((ext_vector_type(8)));
typedef _Float16 half4h __attribute__((ext_vector_type(4)));
typedef float floatx4 __attribute__((ext_vector_type(4)));

__device__ __forceinline__ float fast_tanh(float x) {
    float e = __expf(2.0f * x);
    float r = __builtin_amdgcn_rcpf(e + 1.0f);
    return 1.0f - 2.0f * r;
}

// frag-space byte offset of (batch row m, combined-k k)
__device__ __forceinline__ int fragoff(int m, int k) {
    return (k >> 5) * FB + ((k >> 3) & 3) * 256 + m * 16 + (k & 7) * 2;
}

__global__ void __launch_bounds__(512)
rnn_fused(const int* __restrict__ x, const float* __restrict__ emb,
          const float* __restrict__ W_ih, const float* __restrict__ b_ih,
          const float* __restrict__ W_hh, const float* __restrict__ b_hh,
          const float* __restrict__ W1, const float* __restrict__ b1,
          const float* __restrict__ W2, const float* __restrict__ b2,
          float* __restrict__ out)
{
    __shared__ __align__(16) _Float16 uf[2][FRB][512];  // frag-order, double-buffered
    __shared__ int      xs[SEQ * BM];
    __shared__ float    h1s[BM][H1P];

    const int tid  = threadIdx.x;
    const int lane = tid & 63;
    const int w    = tid >> 6;
    const int ln15 = lane & 15;
    const int q    = lane >> 4;
    const int row0 = blockIdx.x * BM;

    // 19 tiles of 16 cols: waves 0-2 get 3, waves 3-7 get 2 (tiles 0..18, no pad tile)
    const int nt = (w < 3) ? 3 : 2;
    const int t0 = (w < 3) ? 3 * w : 2 * w + 3;

    // zero both u buffers (zeros at k=100..111, 412..447 must persist)
    for (int i = tid; i < 2 * FRB * 512 / 2; i += 512) ((unsigned int*)uf)[i] = 0u;
    for (int i = tid; i < SEQ * BM; i += 512)
        xs[i] = x[(size_t)(i >> 4) * BATCH + row0 + (i & 15)];

    // ---- W resident in registers (A-operand: lane ln15 = row n, k = kk*32+q*8+j)
    half8   Wb[NTMAX][NFRAG];
    floatx4 biasv[NTMAX];
#pragma unroll
    for (int tt = 0; tt < NTMAX; ++tt) {
        const int nb = (t0 + tt) * 16;
#pragma unroll
        for (int r = 0; r < 4; ++r) {
            const int col = nb + 4 * q + r;
            biasv[tt][r] = (col < HID) ? (b_ih[col] + b_hh[col]) : 0.0f;
        }
        const int n = nb + ln15;
#pragma unroll
        for (int kk = 0; kk < NFRAG; ++kk) {
            union { half8 h; unsigned int d[4]; } cv;
#pragma unroll
            for (int j = 0; j < 8; ++j) {
                const int k = kk * 32 + q * 8 + j;
                float v = 0.0f;
                if (n < HID) {
                    if (k < EMB)                        v = W_ih[n * EMB + k];
                    else if (k >= 112 && k < 112 + HID) v = W_hh[n * HID + (k - 112)];
                }
                cv.h[j] = (_Float16)v;
            }
            asm volatile("" : "+v"(cv.d[0]), "+v"(cv.d[1]), "+v"(cv.d[2]), "+v"(cv.d[3]));
            Wb[tt][kk] = cv.h;
        }
    }

    // ---- precomputed LDS byte offsets
    char* ub = (char*)uf;
    const int rdo = lane * 16;                       // read base within a buffer
    int hwo[NTMAX];                                  // h-write offsets (batch=ln15, cols 4q..4q+3 of tile)
#pragma unroll
    for (int tt = 0; tt < NTMAX; ++tt)
        hwo[tt] = fragoff(ln15, 112 + (t0 + tt) * 16 + 4 * q);
    const int gr = tid / 25, gc = tid - gr * 25;     // xe stager: row, float4-chunk
    const int xwo = fragoff(gr, 4 * gc);
    __syncthreads();

    // xe for t=0 into buffer 0
    if (tid < 400) {
        const int idx = xs[gr];
        const float4 f = ((const float4*)emb)[(size_t)idx * 25 + gc];
        half4h hv; hv[0] = (_Float16)f.x; hv[1] = (_Float16)f.y;
                   hv[2] = (_Float16)f.z; hv[3] = (_Float16)f.w;
        *(half4h*)(ub + xwo) = hv;
    }
    __syncthreads();

    for (int t = 0; t < SEQ; ++t) {
        const int p = t & 1;
        const char* rb = ub + p * BUFB + rdo;
        char*       wb = ub + (1 - p) * BUFB;

        // issue xe_{t+1} gather first — vmcnt wait lands after the MFMA phase
        float4 pf;
        const bool do_pf = (t + 1 < SEQ) && (tid < 400);
        if (do_pf) {
            const int idx = xs[(t + 1) * BM + gr];
            pf = ((const float4*)emb)[(size_t)idx * 25 + gc];
        }

        floatx4 acc[NTMAX];
#pragma unroll
        for (int tt = 0; tt < NTMAX; ++tt) acc[tt] = biasv[tt];

        // pipelined frag reads (single base + immediate offsets, conflict-free)
        half8 af[NFRAG];
#pragma unroll
        for (int kk = 0; kk < PD; ++kk) af[kk] = *(const half8*)(rb + kk * FB);
#pragma unroll
        for (int kk = 0; kk < NFRAG; ++kk) {
            if (kk + PD < NFRAG) af[kk + PD] = *(const half8*)(rb + (kk + PD) * FB);
#pragma unroll
            for (int tt = 0; tt < NTMAX; ++tt)
                if (tt < nt)   // wave-uniform
                    acc[tt] = __builtin_amdgcn_mfma_f32_16x16x32_f16(Wb[tt][kk], af[kk], acc[tt], 0, 0, 0);
        }

        if (do_pf) {
            half4h hv; hv[0] = (_Float16)pf.x; hv[1] = (_Float16)pf.y;
                       hv[2] = (_Float16)pf.z; hv[3] = (_Float16)pf.w;
            *(half4h*)(wb + xwo) = hv;
        }
        // tanh + packed h-writes (D transposed: lane ln15 = batch row, 4 consecutive cols)
#pragma unroll
        for (int tt = 0; tt < NTMAX; ++tt) {
            if (tt < nt) {
                half4h hv;
#pragma unroll
                for (int r = 0; r < 4; ++r) hv[r] = (_Float16)fast_tanh(acc[tt][r]);
                *(half4h*)(wb + hwo[tt]) = hv;
            }
        }
        __syncthreads();   // single barrier per step
    }

    // ---- head: h1 = relu(h @ W1^T + b1); final h is in buffer 0 (frag layout)
    {
        const int hro = fragoff(ln15, 112 + q * 8);   // + kkh*FB walks k by 32
        floatx4 hacc[2];
        int ncol[2];
#pragma unroll
        for (int tt = 0; tt < 2; ++tt) {
            const int n = (w * 2 + tt) * 16 + ln15;
            ncol[tt] = n;
            const float b = b1[n];
            hacc[tt][0] = b; hacc[tt][1] = b; hacc[tt][2] = b; hacc[tt][3] = b;
        }
#pragma unroll
        for (int kk = 0; kk < NHF; ++kk) {
            const half8 a = *(const half8*)(ub + hro + kk * FB);
#pragma unroll
            for (int tt = 0; tt < 2; ++tt) {
                half8 bv;
#pragma unroll
                for (int j = 0; j < 8; ++j) {
                    const int k = kk * 32 + q * 8 + j;
                    bv[j] = (_Float16)((k < HID) ? W1[ncol[tt] * HID + k] : 0.0f);
                }
                hacc[tt] = __builtin_amdgcn_mfma_f32_16x16x32_f16(bv, a, hacc[tt], 0, 0, 0);
            }
        }
        // D transposed: lane ln15 = batch row, cols (2w+tt)*16 + 4q + r
#pragma unroll
        for (int tt = 0; tt < 2; ++tt) {
            float4 fv;
            fv.x = fmaxf(hacc[tt][0], 0.0f); fv.y = fmaxf(hacc[tt][1], 0.0f);
            fv.z = fmaxf(hacc[tt][2], 0.0f); fv.w = fmaxf(hacc[tt][3], 0.0f);
            *(float4*)&h1s[ln15][(w * 2 + tt) * 16 + 4 * q] = fv;
        }
    }
    __syncthreads();

    // ---- out = h1 @ W2^T + b2: 16 rows x 2 cols
    if (tid < 32) {
        const int r = tid & 15, o = tid >> 4;
        float a = b2[o];
        const float* ww = W2 + (size_t)o * NH1;
        for (int k = 0; k < NH1; ++k) a += h1s[r][k] * ww[k];
        out[(size_t)(row0 + r) * 2 + o] = a;
    }
}

extern "C" void kernel_launch(void* const* d_in, const int* in_sizes, int n_in,
                              void* d_out, int out_size, void* d_ws, size_t ws_size,
                              hipStream_t stream) {
    const int*   x    = (const int*)d_in[0];
    const float* emb  = (const float*)d_in[1];
    const float* W_ih = (const float*)d_in[2];
    const float* b_ih = (const float*)d_in[3];
    const float* W_hh = (const float*)d_in[4];
    const float* b_hh = (const float*)d_in[5];
    const float* W1   = (const float*)d_in[6];
    const float* b1   = (const float*)d_in[7];
    const float* W2   = (const float*)d_in[8];
    const float* b2   = (const float*)d_in[9];
    float* outp = (float*)d_out;

    hipLaunchKernelGGL(rnn_fused, dim3(BATCH / BM), dim3(512), 0, stream,
                       x, emb, W_ih, b_ih, W_hh, b_hh, W1, b1, W2, b2, outp);
}